// Round 9
// baseline (513.429 us; speedup 1.0000x reference)
//
#include <hip/hip_runtime.h>
#include <stdint.h>

#define D_DIM 1024
#define INV_T 14.2857142857142857f
#define QSCALE 32.0f
#define EPI_SCALE (INV_T / (QSCALE * QSCALE))   // dequant (32a)(32b) + /T
#define NP 8                                    // 8 K-pairs of 128

typedef __attribute__((ext_vector_type(4))) float f32x4;
typedef __attribute__((ext_vector_type(4))) int i32x4;
typedef __attribute__((ext_vector_type(8))) int i32x8;

// ---------------- Kernel 1: L2-normalize rows (fp32 -> fp8 e4m3 x32) + diagonal dot ----------------
__global__ __launch_bounds__(256) void norm_diag_kernel(
    const float* __restrict__ A, const float* __restrict__ T,
    unsigned int* __restrict__ An, unsigned int* __restrict__ Tn,
    float* __restrict__ diag)
{
  const int row = blockIdx.x;
  const int tid = threadIdx.x;              // 256 threads x 4 elems (D=1024)
  const size_t base = (size_t)row * D_DIM;
  const float4 av = ((const float4*)(A + base))[tid];
  const float4 tv = ((const float4*)(T + base))[tid];
  float sa = av.x*av.x + av.y*av.y + av.z*av.z + av.w*av.w;
  float st = tv.x*tv.x + tv.y*tv.y + tv.z*tv.z + tv.w*tv.w;
  float sd = av.x*tv.x + av.y*tv.y + av.z*tv.z + av.w*tv.w;
  #pragma unroll
  for (int m = 1; m < 64; m <<= 1) {
    sa += __shfl_xor(sa, m, 64);
    st += __shfl_xor(st, m, 64);
    sd += __shfl_xor(sd, m, 64);
  }
  __shared__ float red[3][4];
  const int wid = tid >> 6;
  if ((tid & 63) == 0) { red[0][wid] = sa; red[1][wid] = st; red[2][wid] = sd; }
  __syncthreads();
  sa = red[0][0] + red[0][1] + red[0][2] + red[0][3];
  st = red[1][0] + red[1][1] + red[1][2] + red[1][3];
  sd = red[2][0] + red[2][1] + red[2][2] + red[2][3];
  const float ra = rsqrtf(sa), rt = rsqrtf(st);
  if (tid == 0) diag[row] = sd * ra * rt * INV_T;   // diag term in exact fp32
  const float qa = ra * QSCALE, qt = rt * QSCALE;
  unsigned int ao = __builtin_amdgcn_cvt_pk_fp8_f32(av.x*qa, av.y*qa, 0, 0);
  ao = __builtin_amdgcn_cvt_pk_fp8_f32(av.z*qa, av.w*qa, ao, 1);
  unsigned int to = __builtin_amdgcn_cvt_pk_fp8_f32(tv.x*qt, tv.y*qt, 0, 0);
  to = __builtin_amdgcn_cvt_pk_fp8_f32(tv.z*qt, tv.w*qt, to, 1);
  An[row * 256 + tid] = ao;   // plain row-major fp8
  Tn[row * 256 + tid] = to;
}

// ---------------- Kernel 2: 128x128 MX-fp8 (K=128) double-buffered GEMM + exp + row/col sums ----------------
__device__ __forceinline__ void gload_lds16(const void* g, void* l) {
  __builtin_amdgcn_global_load_lds(
      (const __attribute__((address_space(1))) unsigned int*)g,
      (__attribute__((address_space(3))) unsigned int*)l, 16, 0, 0);
}

#define SBAR asm volatile("s_barrier" ::: "memory")

// Stage K-pair S (128 rows x 128 B per operand) into bufpair BP (0/1).
// Per operand 1024 16B-chunks, 4/thread (8 vmcnt ops/thread total).
// LDS dest linear (HW constraint); swizzle on the GLOBAL source:
// LDS chunk (r,c) holds global chunk (r, c ^ (r&7))  [rule #21].
#define STAGE_PAIR(S, BP) do {                                                  \
    const unsigned char* _a = aP + (size_t)(S) * 128;                           \
    const unsigned char* _b = bP + (size_t)(S) * 128;                           \
    const int _bb = (BP) * 32768;                                               \
    _Pragma("unroll")                                                           \
    for (int _i = 0; _i < 4; ++_i) {                                            \
      const int _ci = _i*256 + tid;                                             \
      const int _r = _ci >> 3, _c = _ci & 7;                                    \
      const size_t _go = (size_t)_r * D_DIM + ((_c ^ (_r & 7)) << 4);           \
      gload_lds16(_a + _go, &lds[_bb + _ci*16]);                                \
      gload_lds16(_b + _go, &lds[_bb + 16384 + _ci*16]);                        \
    }                                                                           \
  } while (0)

__global__ __launch_bounds__(256, 2) void gemm_lse_kernel(
    const unsigned char* __restrict__ An, const unsigned char* __restrict__ Tn,
    float* __restrict__ Srow, float* __restrict__ Scol, int nbc)
{
  // 2 bufpairs x (2 ops x 128 rows x 128 B) = 64 KB -> 2 blocks/CU
  __shared__ unsigned char lds[65536];

  // XCD-aware bijective swizzle (gridDim.x = 4096, %8 == 0)
  const int nwg = gridDim.x;
  const int bid = blockIdx.x;
  const int cpx = nwg >> 3;
  const int swz = (bid & 7) * cpx + (bid >> 3);
  const int brow = swz / nbc;
  const int bcol = swz - brow * nbc;

  const int tid  = threadIdx.x;
  const int lane = tid & 63;
  const int wid  = tid >> 6;        // 4 waves, 2x2; each wave owns 64x64 output
  const int wr   = wid >> 1, wc = wid & 1;
  const int lcol = lane & 15, lrow = lane >> 4;

  const unsigned char* aP = An + (size_t)brow * 128 * D_DIM;
  const unsigned char* bP = Tn + (size_t)bcol * 128 * D_DIM;

  f32x4 acc[4][4] = {};

  // Prologue: pair0 -> bp0, pair1 -> bp1 (16 ops/thread); vmcnt(8) retires
  // pair0 (in-order), keeps pair1's 8 in flight.
  STAGE_PAIR(0, 0);
  STAGE_PAIR(1, 1);
  asm volatile("s_waitcnt vmcnt(8)" ::: "memory");
  SBAR;

  // Per pair s: lane slot j (0..15 lo-half, 16..31 hi-half) holds
  // pair-k = {lrow*16+j, 64+lrow*16+(j-16)}; same mapping for A and B, so any
  // deviation from HW's nominal k-order is a uniform permutation and cancels.
  #pragma unroll
  for (int s = 0; s < NP; ++s) {
    const int bb = (s & 1) * 32768;
    i32x8 af[4], bf[4];
    #pragma unroll
    for (int m = 0; m < 4; ++m) {
      const int row = wr*64 + m*16 + lcol;
      const int c0 = lrow ^ (row & 7);          // chunk of bytes lrow*16..
      const int c1 = (4 + lrow) ^ (row & 7);    // chunk of bytes 64+lrow*16..
      const i32x4 lo = *(const i32x4*)&lds[bb + row*128 + c0*16];
      const i32x4 hi = *(const i32x4*)&lds[bb + row*128 + c1*16];
      af[m][0]=lo[0]; af[m][1]=lo[1]; af[m][2]=lo[2]; af[m][3]=lo[3];
      af[m][4]=hi[0]; af[m][5]=hi[1]; af[m][6]=hi[2]; af[m][7]=hi[3];
    }
    #pragma unroll
    for (int n = 0; n < 4; ++n) {
      const int row = wc*64 + n*16 + lcol;
      const int c0 = lrow ^ (row & 7);
      const int c1 = (4 + lrow) ^ (row & 7);
      const i32x4 lo = *(const i32x4*)&lds[bb + 16384 + row*128 + c0*16];
      const i32x4 hi = *(const i32x4*)&lds[bb + 16384 + row*128 + c1*16];
      bf[n][0]=lo[0]; bf[n][1]=lo[1]; bf[n][2]=lo[2]; bf[n][3]=lo[3];
      bf[n][4]=hi[0]; bf[n][5]=hi[1]; bf[n][6]=hi[2]; bf[n][7]=hi[3];
    }
    __builtin_amdgcn_s_setprio(1);
    #pragma unroll
    for (int m = 0; m < 4; ++m)
      #pragma unroll
      for (int n = 0; n < 4; ++n)
        acc[m][n] = __builtin_amdgcn_mfma_scale_f32_16x16x128_f8f6f4(
            af[m], bf[n], acc[m][n], 0, 0,         // cbsz=fp8, blgp=fp8
            0, 0x7F7F7F7F, 0, 0x7F7F7F7F);         // all scales = 2^0 = 1.0
    __builtin_amdgcn_s_setprio(0);
    // Seal this bufpair's reads, then refill it with pair s+2.
    asm volatile("s_waitcnt lgkmcnt(0)" ::: "memory");
    SBAR;
    if (s + 2 < NP) {
      STAGE_PAIR(s + 2, s & 1);
      // Outstanding: pair s+1's 8 + pair s+2's 8 -> wait s+1 resident,
      // keep s+2 in flight (never vmcnt(0) mid-loop).
      asm volatile("s_waitcnt vmcnt(8)" ::: "memory");
    } else {
      asm volatile("s_waitcnt vmcnt(0)" ::: "memory");  // tail drain
    }
    SBAR;
  }

  // ---- Epilogue: e = exp(acc * EPI_SCALE); row/col partial sums -> atomics ----
  // C/D mapping (shape-determined): col = lane&15, row = (lane>>4)*4 + reg
  float rowsum[4][4];
  float colsum[4];
  #pragma unroll
  for (int m = 0; m < 4; ++m)
    #pragma unroll
    for (int r = 0; r < 4; ++r) rowsum[m][r] = 0.f;
  #pragma unroll
  for (int n = 0; n < 4; ++n) {
    float cs = 0.f;
    #pragma unroll
    for (int m = 0; m < 4; ++m)
      #pragma unroll
      for (int r = 0; r < 4; ++r) {
        const float e = __expf(acc[m][n][r] * EPI_SCALE);
        rowsum[m][r] += e;
        cs += e;
      }
    colsum[n] = cs;
  }
  #pragma unroll
  for (int m = 0; m < 4; ++m)
    #pragma unroll
    for (int r = 0; r < 4; ++r) {
      float v = rowsum[m][r];
      v += __shfl_xor(v, 1, 64);
      v += __shfl_xor(v, 2, 64);
      v += __shfl_xor(v, 4, 64);
      v += __shfl_xor(v, 8, 64);
      if (lcol == 0)
        atomicAdd(&Srow[brow*128 + wr*64 + m*16 + lrow*4 + r], v);
    }
  #pragma unroll
  for (int n = 0; n < 4; ++n) {
    float v = colsum[n];
    v += __shfl_xor(v, 16, 64);
    v += __shfl_xor(v, 32, 64);
    if (lane < 16)
      atomicAdd(&Scol[bcol*128 + wc*64 + n*16 + lcol], v);
  }
}

// ---------------- Kernel 3: loss = mean(0.5*(log Srow + log Scol) - diag) ----------------
__global__ __launch_bounds__(256) void loss_kernel(
    const float* __restrict__ Srow, const float* __restrict__ Scol,
    const float* __restrict__ diag, float* __restrict__ out, int B)
{
  float s = 0.f;
  for (int i = threadIdx.x; i < B; i += 256)
    s += 0.5f * (__logf(Srow[i]) + __logf(Scol[i])) - diag[i];
  #pragma unroll
  for (int m = 1; m < 64; m <<= 1) s += __shfl_xor(s, m, 64);
  __shared__ float red[4];
  if ((threadIdx.x & 63) == 0) red[threadIdx.x >> 6] = s;
  __syncthreads();
  if (threadIdx.x == 0) out[0] = (red[0] + red[1] + red[2] + red[3]) / (float)B;
}

extern "C" void kernel_launch(void* const* d_in, const int* in_sizes, int n_in,
                              void* d_out, int out_size, void* d_ws, size_t ws_size,
                              hipStream_t stream) {
  const float* A = (const float*)d_in[0];
  const float* T = (const float*)d_in[1];
  const int B = in_sizes[0] / D_DIM;     // 8192
  const int nbc = B / 128;               // 64

  char* ws = (char*)d_ws;
  unsigned char* An = (unsigned char*)ws;                       // B*D fp8 = 8 MB
  unsigned char* Tn = An + (size_t)B * D_DIM;                   // 8 MB
  float* Srow = (float*)(ws + (size_t)2 * B * D_DIM);
  float* Scol = Srow + B;
  float* diag = Scol + B;

  hipMemsetAsync(Srow, 0, (size_t)2 * B * sizeof(float), stream);
  norm_diag_kernel<<<B, 256, 0, stream>>>(A, T, (unsigned int*)An, (unsigned int*)Tn, diag);
  gemm_lse_kernel<<<nbc * nbc, 256, 0, stream>>>(An, Tn, Srow, Scol, nbc);
  loss_kernel<<<1, 256, 0, stream>>>(Srow, Scol, diag, (float*)d_out, B);
}